// Round 19
// baseline (172.302 us; speedup 1.0000x reference)
//
#include <hip/hip_runtime.h>
#include <hip/hip_bf16.h>
#include <hip/hip_cooperative_groups.h>

namespace cg = cooperative_groups;

// GraphAttentionLayer collapse: out[b,i,o] = (S_mask[b,i,o] < 0) ? 1 : 0,
// S_mask = sum_{adj[i,j]==0} hW[b,j,o]  (|9e15*S_mask| >> |softmax term| => sigmoid saturates).
// Exact i8 MFMA path (digits d0,d1,d2 of rint(hW*2^16); i32 MFMA exact; |S|<=2048 -> f64 fixup).
// ROUND-18 BUG FIX: phase A2 covered only 1024 of 4096 hwrepack units (v = bid*4+sub*2+u,
// u<2) -> batches 1..3 never computed (R4 bug class: coverage arithmetic). Fix:
// u<8, v = bid*16 + sub*8 + u -> 256 blocks x 16 units = 4096. All else unchanged.

#define GN 4096
#define GB 4
#define FIN 128
#define FOUT 64

typedef int i32x4 __attribute__((ext_vector_type(4)));
typedef unsigned int uint32x4 __attribute__((ext_vector_type(4)));
typedef float f32x4 __attribute__((ext_vector_type(4)));

__global__ __launch_bounds__(512, 1)
void fused_kernel(const int* __restrict__ adj, const float* __restrict__ h,
                  const float* __restrict__ W, unsigned long long* __restrict__ tmask,
                  double* __restrict__ hW, unsigned char* __restrict__ Bp,
                  float* __restrict__ out) {
    __shared__ __align__(16) unsigned char SMEM[49152];   // phase A overlay / phase B merge
    __shared__ unsigned int nflag;
    __shared__ unsigned int flagbuf[128];
    __shared__ double fred[8];

    const int t = threadIdx.x;
    const int bid = (int)blockIdx.x;

    // ================= PHASE A1: pack (R17-verified math, 512-thread rescale) ========
    // block (rt,cp): rows rt*64..+64, cols cp*1024..+1024.
    // bit (r*16+jj) of tmask[rt*64+s][l] = (adj[rt*64+r*16+(l&15)][s*64+(l>>4)*16+jj]==0)
    {
        unsigned short (*m16)[68] = (unsigned short (*)[68])SMEM;   // 64*68*2 = 8704 B
        const int rt = bid >> 2, cp = bid & 3;
        const int wrow = t >> 6;      // 0..7, wave-uniform
        const int j16 = t & 63;
#pragma unroll
        for (int p = 0; p < 8; ++p) {
            const int row = p * 8 + wrow;
            const i32x4* src = (const i32x4*)(adj + (size_t)(rt * 64 + row) * GN
                                              + cp * 1024 + j16 * 16);
            unsigned int b16 = 0;
#pragma unroll
            for (int q = 0; q < 4; ++q) {
                i32x4 v = src[q];
                b16 |= (v.x == 0 ? 1u : 0u) << (q * 4);
                b16 |= (v.y == 0 ? 2u : 0u) << (q * 4);
                b16 |= (v.z == 0 ? 4u : 0u) << (q * 4);
                b16 |= (v.w == 0 ? 8u : 0u) << (q * 4);
            }
            m16[row][j16] = (unsigned short)b16;
        }
        __syncthreads();
        // phase 2 (verified formulas): 1024 words / 512 thr = 2 each
#pragma unroll
        for (int it = 0; it < 2; ++it) {
            const int idx = it * 512 + t;
            const int sloc = idx >> 6, l = idx & 63;      // sloc in [0,16)
            const int row16 = l & 15, g = l >> 4;
            unsigned long long res = 0ull;
#pragma unroll
            for (int r = 0; r < 4; ++r)
                res |= (unsigned long long)m16[r * 16 + row16][sloc * 4 + g] << (r * 16);
            tmask[((size_t)rt * 64 + cp * 16 + sloc) * 64 + l] = res;
        }
        __syncthreads();   // m16 region dead; reuse SMEM below
    }

    // ====== PHASE A2: hwrepack (R7/R8-verified body; 2 subgroups x 8 iters = 16 units) ===
    // vblock v: b = v>>10, q4 = v&1023; 4 rows q4*4..+3; thread (grp = tt>>6, o = tt&63).
    // Bp[(b*64+p)*12288 + pl*4096 + cg*1024 + g*256 + col16*16 + qr*4]  (verified R7..R17)
    {
        float (*hs)[4][FIN] = (float (*)[4][FIN])SMEM;                    // 2*4*128*4 = 4 KB
        unsigned int (*dg)[4][64] = (unsigned int (*)[4][64])(SMEM + 8192); // 2 KB
        const int sub = t >> 8;           // 0/1
        const int tt = t & 255;
        const int grp = tt >> 6, o = tt & 63;

#pragma unroll
        for (int u = 0; u < 8; ++u) {
            const int v = bid * 16 + sub * 8 + u;     // FIX: 256 blocks x 16 = 4096 units
            const int b = v >> 10, q4 = v & 1023;
            if (tt < 128) {
                const f32x4* src = (const f32x4*)(h + ((size_t)b * GN + q4 * 4) * FIN);
                f32x4* dst = (f32x4*)&hs[sub][0][0];
                dst[tt] = src[tt];
            }
            __syncthreads();
            double a0 = 0, a1 = 0, a2 = 0, a3 = 0;
#pragma unroll
            for (int i = 0; i < FIN; i += 4) {
                a0 = fma((double)hs[sub][grp][i],     (double)W[i * FOUT + o],       a0);
                a1 = fma((double)hs[sub][grp][i + 1], (double)W[(i + 1) * FOUT + o], a1);
                a2 = fma((double)hs[sub][grp][i + 2], (double)W[(i + 2) * FOUT + o], a2);
                a3 = fma((double)hs[sub][grp][i + 3], (double)W[(i + 3) * FOUT + o], a3);
            }
            double acc = (a0 + a1) + (a2 + a3);
            hW[((size_t)b * GN + q4 * 4 + grp) * FOUT + o] = acc;

            int qi = (int)llrint(acc * 65536.0);
            int d0 = ((qi + 128) & 255) - 128; qi = (qi - d0) >> 8;
            int d1 = ((qi + 128) & 255) - 128; qi = (qi - d1) >> 8;  // qi now = d2
            dg[sub][grp][o] = (unsigned int)(d0 & 255) | ((unsigned int)(d1 & 255) << 8)
                            | ((unsigned int)(qi & 255) << 16);
            __syncthreads();
            if (grp < 3) {   // grp = digit plane
                unsigned int w = 0;
#pragma unroll
                for (int rr = 0; rr < 4; ++rr)
                    w |= ((dg[sub][rr][o] >> (grp * 8)) & 255u) << (rr * 8);
                const int p = q4 >> 4, g = (q4 >> 2) & 3, qr = q4 & 3;
                const int cgi = o >> 4, col16 = o & 15;
                *(unsigned int*)(Bp + ((size_t)b * 64 + p) * 12288 + grp * 4096
                                 + cgi * 1024 + g * 256 + col16 * 16 + qr * 4) = w;
            }
            __syncthreads();   // hs/dg reused next u
        }
    }

    // ================= grid-wide barrier: tmask/Bp/hW fully written =================
    cg::this_grid().sync();

    // ================= PHASE B: gemm depth-4 (R10 verbatim) + in-block fixup =========
    {
        unsigned char* lds = SMEM;
        const int tid = t, lane = tid & 63, wv = tid >> 6;
        const int cgr = wv & 3, kg = wv >> 2;
        const int rt = bid >> 2, b = bid & 3;
        if (tid == 0) nflag = 0;

        const unsigned char* bptr = Bp + (size_t)b * 786432 + kg * 12288 + cgr * 1024 + lane * 16;
        const unsigned long long* mptr = tmask + (size_t)rt * 4096 + kg * 64 + lane;

        i32x4 acc[4][3];
#pragma unroll
        for (int r = 0; r < 4; ++r)
#pragma unroll
            for (int pl = 0; pl < 3; ++pl) {
                i32x4 z = {0, 0, 0, 0};
                acc[r][pl] = z;
            }

#define DECLSET(S) i32x4 b##S##0, b##S##1, b##S##2; unsigned long long m##S;
#define LOADSET(S, T) { const unsigned char* g_ = bptr + (size_t)(T) * 24576;          \
        b##S##0 = *(const i32x4*)(g_);                                                 \
        b##S##1 = *(const i32x4*)(g_ + 4096);                                          \
        b##S##2 = *(const i32x4*)(g_ + 8192);                                          \
        m##S = mptr[(size_t)(T) * 128]; }

        DECLSET(A) DECLSET(B) DECLSET(C) DECLSET(D)
        LOADSET(A, 0) LOADSET(B, 1) LOADSET(C, 2) LOADSET(D, 3)

        auto dostep = [&](unsigned long long mw, i32x4 v0, i32x4 v1, i32x4 v2) {
            const unsigned int mlo = (unsigned int)mw, mhi = (unsigned int)(mw >> 32);
#pragma unroll
            for (int r = 0; r < 4; ++r) {
                unsigned int half = (r >> 1) ? mhi : mlo;
                unsigned int w16 = (r & 1) ? (half >> 16) : (half & 0xFFFFu);
                uint32x4 u;
#pragma unroll
                for (int q = 0; q < 4; ++q)
                    u[q] = (((w16 >> (4 * q)) & 0xFu) * 0x00204081u) & 0x01010101u;
                i32x4 af = __builtin_bit_cast(i32x4, u);
                acc[r][0] = __builtin_amdgcn_mfma_i32_16x16x64_i8(af, v0, acc[r][0], 0, 0, 0);
                acc[r][1] = __builtin_amdgcn_mfma_i32_16x16x64_i8(af, v1, acc[r][1], 0, 0, 0);
                acc[r][2] = __builtin_amdgcn_mfma_i32_16x16x64_i8(af, v2, acc[r][2], 0, 0, 0);
            }
        };

        for (int T = 0; T < 32; T += 4) {
            dostep(mA, bA0, bA1, bA2);
            if (T + 4 < 32) LOADSET(A, T + 4)
            dostep(mB, bB0, bB1, bB2);
            if (T + 5 < 32) LOADSET(B, T + 5)
            dostep(mC, bC0, bC1, bC2);
            if (T + 6 < 32) LOADSET(C, T + 6)
            dostep(mD, bD0, bD1, bD2);
            if (T + 7 < 32) LOADSET(D, T + 7)
        }
#undef DECLSET
#undef LOADSET

        // merge kg=1 partials into kg=0 via LDS
        __syncthreads();
        if (kg == 1) {
            unsigned char* dst = lds + cgr * 12288 + lane * 192;
#pragma unroll
            for (int r = 0; r < 4; ++r)
#pragma unroll
                for (int pl = 0; pl < 3; ++pl)
                    *(i32x4*)(dst + (r * 3 + pl) * 16) = acc[r][pl];
        }
        __syncthreads();
        if (kg == 0) {
            const unsigned char* s2 = lds + cgr * 12288 + lane * 192;
#pragma unroll
            for (int r = 0; r < 4; ++r)
#pragma unroll
                for (int pl = 0; pl < 3; ++pl) {
                    i32x4 v = *(const i32x4*)(s2 + (r * 3 + pl) * 16);
#pragma unroll
                    for (int q = 0; q < 4; ++q) acc[r][pl][q] += v[q];
                }

            const int o = cgr * 16 + (lane & 15);
#pragma unroll
            for (int r = 0; r < 4; ++r) {
#pragma unroll
                for (int q = 0; q < 4; ++q) {
                    double S = (double)acc[r][0][q] + 256.0 * (double)acc[r][1][q]
                             + 65536.0 * (double)acc[r][2][q];     // exact integer
                    int i = rt * 64 + r * 16 + (lane >> 4) * 4 + q;  // C/D row map (m89)
                    size_t oi = ((size_t)b * GN + i) * FOUT + o;
                    out[oi] = S < 0.0 ? 1.0f : 0.0f;
                    if (fabs(S) <= 2048.0) {
                        unsigned int idx = atomicAdd(&nflag, 1u);
                        if (idx < 128) flagbuf[idx] = ((unsigned int)i << 6) | (unsigned int)o;
                    }
                }
            }
        }

        // in-block exact fixup (expected ~0.2 items/block)
        __syncthreads();
        unsigned int nf = nflag;
        if (nf > 128) nf = 128;
        for (unsigned int f = 0; f < nf; ++f) {
            unsigned int e = flagbuf[f];
            int o = e & 63;
            int i = (int)(e >> 6);
            int row16 = i & 15, r = (i >> 4) & 3;
            int s = tid >> 3, lg = (tid >> 1) & 3, hf = tid & 1;
            unsigned long long w = tmask[((size_t)rt * 64 + s) * 64 + (lg * 16 + row16)];
            double ps = 0.0;
            const double* hwc = hW + ((size_t)b * GN + s * 64 + lg * 16) * FOUT + o;
#pragma unroll
            for (int jj = hf * 8; jj < hf * 8 + 8; ++jj) {
                if ((w >> (r * 16 + jj)) & 1ull)
                    ps += hwc[(size_t)jj * FOUT];
            }
#pragma unroll
            for (int d = 32; d >= 1; d >>= 1) ps += __shfl_down(ps, d, 64);
            if (lane == 0) fred[wv] = ps;
            __syncthreads();
            if (tid == 0) {
                double tot = ((fred[0] + fred[1]) + (fred[2] + fred[3]))
                           + ((fred[4] + fred[5]) + (fred[6] + fred[7]));
                out[((size_t)b * GN + i) * FOUT + o] = tot < 0.0 ? 1.0f : 0.0f;
            }
            __syncthreads();
        }
    }
}

extern "C" void kernel_launch(void* const* d_in, const int* in_sizes, int n_in,
                              void* d_out, int out_size, void* d_ws, size_t ws_size,
                              hipStream_t stream) {
    const int*   adj = (const int*)d_in[1];     // [4096,4096]
    const float* h   = (const float*)d_in[0];   // [4,4096,128]
    const float* W   = (const float*)d_in[2];   // [128,64]
    float* out = (float*)d_out;                 // [4,4096,64] f32

    char* ws = (char*)d_ws;
    double* hW                = (double*)ws;                          // 8 MB @ 0
    unsigned char* Bp         = (unsigned char*)(ws + 8388608);       // 3 MB @ 8M
    unsigned long long* tmask = (unsigned long long*)(ws + 12582912); // 2 MB @ 12M

    void* kargs[] = {(void*)&adj, (void*)&h, (void*)&W,
                     (void*)&tmask, (void*)&hW, (void*)&Bp, (void*)&out};
    hipLaunchCooperativeKernel((void*)fused_kernel, dim3(256), dim3(512),
                               kargs, 0, stream);
}

// Round 22
// 57.406 us; speedup vs baseline: 3.0015x; 3.0015x over previous
//
#include <hip/hip_runtime.h>
#include <hip/hip_bf16.h>

// GraphAttentionLayer collapse: out[b,i,o] = (S_mask[b,i,o] < 0) ? 1 : 0,
// S_mask = sum_{adj[i,j]==0} hW[b,j,o]  (|9e15*S_mask| >> |softmax term| => sigmoid saturates).
// Exact i8 MFMA path (digits d0,d1,d2 of rint(hW*2^16); i32 MFMA exact; |S|<=2048 -> f64 fixup).
// Round-22: R21's absmax fail isolated to the UNVERIFIED f64-MFMA lane map (m89 was
// never verified for f64; paired C/D regs may interleave rows, or transpose). This
// version SELF-IDENTIFIES the map at runtime: per-lane reference dot from the staged
// LDS operands + wave ballot-AND selects among 4 candidate maps; D bounces through an
// LDS tile so the (verified) digit/store epilogue is map-independent. VALU fallback
// guarantees correctness if no map matches. pack = R17-verified; gemm = R10 frozen.

#define GN 4096
#define GB 4
#define FIN 128
#define FOUT 64

typedef int i32x4 __attribute__((ext_vector_type(4)));
typedef unsigned int uint32x4 __attribute__((ext_vector_type(4)));
typedef float f32x4 __attribute__((ext_vector_type(4)));
typedef double f64x4 __attribute__((ext_vector_type(4)));

// ---- kernel 1: adj -> transposed bitmask (R17-verified, 1024 threads) ----
__global__ __launch_bounds__(1024) void pack_kernel(const int* __restrict__ adj,
                                                    unsigned long long* __restrict__ tmask) {
    __shared__ unsigned short m16[64][68];
    const int t = threadIdx.x;
    const int rt = (int)blockIdx.x >> 2, cp = (int)blockIdx.x & 3;
    const int wrow = t >> 6;      // 0..15, wave-uniform
    const int j16 = t & 63;       // lane

#pragma unroll
    for (int p = 0; p < 4; ++p) {
        const int row = p * 16 + wrow;
        const i32x4* src = (const i32x4*)(adj + (size_t)(rt * 64 + row) * GN
                                          + cp * 1024 + j16 * 16);
        unsigned int b16 = 0;
#pragma unroll
        for (int q = 0; q < 4; ++q) {
            i32x4 v = src[q];
            b16 |= (v.x == 0 ? 1u : 0u) << (q * 4);
            b16 |= (v.y == 0 ? 2u : 0u) << (q * 4);
            b16 |= (v.z == 0 ? 4u : 0u) << (q * 4);
            b16 |= (v.w == 0 ? 8u : 0u) << (q * 4);
        }
        m16[row][j16] = (unsigned short)b16;
    }
    __syncthreads();
    {
        const int sloc = t >> 6, l = t & 63;      // sloc in [0,16)
        const int row16 = l & 15, g = l >> 4;
        unsigned long long res = 0ull;
#pragma unroll
        for (int r = 0; r < 4; ++r)
            res |= (unsigned long long)m16[r * 16 + row16][sloc * 4 + g] << (r * 16);
        tmask[((size_t)rt * 64 + cp * 16 + sloc) * 64 + l] = res;
    }
}

// ---- kernel 2: hW = h @ W via f64 MFMA, map-self-identifying ----
// 256 blocks x 512 thr; block = 64 flattened rows (never crosses batch boundary).
// Wave wv: mt = wv>>1 (16-row subtile), np = wv&1 (32-col half); 32 k-steps x 2 MFMA.
__global__ __launch_bounds__(512, 1) void hwrepack_kernel(const float* __restrict__ h,
                                                          const float* __restrict__ W,
                                                          double* __restrict__ hW,
                                                          unsigned char* __restrict__ Bp) {
    __shared__ float hs[64][132];    // 33 KB
    __shared__ float Wl[FIN][68];    // 34 KB
    __shared__ double Dt[64][66];    // 33 KB bounce tile
    __shared__ int smap;
    const int t = threadIdx.x;
    const int lane = t & 63, wv = t >> 6;
    const int bid = (int)blockIdx.x;

    // stage h rows bid*64..+64 and W, coalesced f32x4 (verified R21 addressing)
    {
        const f32x4* srcH = (const f32x4*)(h + (size_t)bid * 64 * FIN);
        const f32x4* srcW = (const f32x4*)W;
#pragma unroll
        for (int c = 0; c < 4; ++c) {
            int idx = c * 512 + t;                 // f32x4 index in [0,2048)
            f32x4 vh = srcH[idx];
            *(f32x4*)&hs[idx >> 5][(idx & 31) * 4] = vh;
            f32x4 vw = srcW[idx];
            *(f32x4*)&Wl[idx >> 4][(idx & 15) * 4] = vw;
        }
    }
    __syncthreads();

    const int mt = wv >> 1, np = wv & 1;
    const int lr = lane & 15, lk = lane >> 4;
    f64x4 acc0 = {0.0, 0.0, 0.0, 0.0}, acc1 = {0.0, 0.0, 0.0, 0.0};
#pragma unroll
    for (int ks = 0; ks < 32; ++ks) {
        const int kk = ks * 4 + lk;
        double A  = (double)hs[mt * 16 + lr][kk];
        double B0 = (double)Wl[kk][np * 32 + lr];
        double B1 = (double)Wl[kk][np * 32 + 16 + lr];
        acc0 = __builtin_amdgcn_mfma_f64_16x16x4f64(A, B0, acc0, 0, 0, 0);
        acc1 = __builtin_amdgcn_mfma_f64_16x16x4f64(A, B1, acc1, 0, 0, 0);
    }

    // ---- runtime map identification via reference dot of acc0[0]'s claimed position ----
    auto dotref = [&](int row, int col) {
        double s = 0.0;
#pragma unroll 8
        for (int k = 0; k < FIN; ++k)
            s = fma((double)hs[row][k], (double)Wl[k][col], s);
        return s;
    };
    auto allmatch = [&](double ref) {
        double d = fabs(acc0[0] - ref);
        int ok = d <= 1e-6 + 1e-6 * fabs(ref);
        return __ballot(ok) == ~0ull;          // all 64 lanes agree
    };
    int mapid;
    if      (allmatch(dotref(mt * 16 + 4 * lk, np * 32 + lr))) mapid = 0;  // m89-style
    else if (allmatch(dotref(mt * 16 + lk,     np * 32 + lr))) mapid = 1;  // pair-interleaved
    else if (allmatch(dotref(mt * 16 + lr, np * 32 + 4 * lk))) mapid = 2;  // transpose of 0
    else if (allmatch(dotref(mt * 16 + lr, np * 32 + lk)))     mapid = 3;  // transpose of 1
    else mapid = 4;                                                        // fallback: VALU

    if (mapid != 4) {
#pragma unroll
        for (int nt = 0; nt < 2; ++nt) {
            const f64x4 acv = nt ? acc1 : acc0;
#pragma unroll
            for (int q = 0; q < 4; ++q) {
                int row, col;
                if (mapid == 0)      { row = mt * 16 + 4 * lk + q; col = np * 32 + nt * 16 + lr; }
                else if (mapid == 1) { row = mt * 16 + lk + 4 * q; col = np * 32 + nt * 16 + lr; }
                else if (mapid == 2) { row = mt * 16 + lr; col = np * 32 + nt * 16 + 4 * lk + q; }
                else                 { row = mt * 16 + lr; col = np * 32 + nt * 16 + lk + 4 * q; }
                Dt[row][col] = acv[q];
            }
        }
    }
    if (t == 0) smap = mapid;
    __syncthreads();
    const bool fb = (smap == 4);

    // ---- map-independent epilogue: 2 q4-units per thread (coalesced cols) ----
#pragma unroll
    for (int u = 0; u < 2; ++u) {
        const int unit = u * 512 + t;
        const int col = unit & 63, rg = unit >> 6;     // rows rg*4..+3, col
        double v0, v1, v2, v3;
        if (fb) {
            v0 = dotref(rg * 4 + 0, col);
            v1 = dotref(rg * 4 + 1, col);
            v2 = dotref(rg * 4 + 2, col);
            v3 = dotref(rg * 4 + 3, col);
        } else {
            v0 = Dt[rg * 4 + 0][col];
            v1 = Dt[rg * 4 + 1][col];
            v2 = Dt[rg * 4 + 2][col];
            v3 = Dt[rg * 4 + 3][col];
        }
        const int rowbase = bid * 64 + rg * 4;         // flattened, multiple of 4
        const int b = rowbase >> 12;
        const int q4 = (rowbase & 4095) >> 2;
        const int p = q4 >> 4, g = (q4 >> 2) & 3, qr = q4 & 3;

        double* hwp = hW + (size_t)rowbase * FOUT + col;
        hwp[0]        = v0;
        hwp[FOUT]     = v1;
        hwp[2 * FOUT] = v2;
        hwp[3 * FOUT] = v3;

        unsigned int w0 = 0, w1 = 0, w2 = 0;
        double vv[4] = {v0, v1, v2, v3};
#pragma unroll
        for (int rr = 0; rr < 4; ++rr) {
            int qi = (int)llrint(vv[rr] * 65536.0);
            int d0 = ((qi + 128) & 255) - 128; qi = (qi - d0) >> 8;
            int d1 = ((qi + 128) & 255) - 128; qi = (qi - d1) >> 8;  // qi now = d2
            w0 |= (unsigned int)(d0 & 255) << (rr * 8);
            w1 |= (unsigned int)(d1 & 255) << (rr * 8);
            w2 |= (unsigned int)(qi & 255) << (rr * 8);
        }
        const int cg = col >> 4, col16 = col & 15;
        unsigned char* dst = Bp + ((size_t)b * 64 + p) * 12288
                           + cg * 1024 + g * 256 + col16 * 16 + qr * 4;
        *(unsigned int*)(dst)        = w0;
        *(unsigned int*)(dst + 4096) = w1;
        *(unsigned int*)(dst + 8192) = w2;
    }
}

// ---- kernel 3: exact i8-MFMA masked-sum GEMM, depth-4 register pipeline (R10, frozen) ----
__global__ __launch_bounds__(512, 1) void gemm_kernel(const unsigned char* __restrict__ Bp,
                                                      const unsigned long long* __restrict__ tmask,
                                                      const double* __restrict__ hW,
                                                      float* __restrict__ out) {
    __shared__ __align__(16) unsigned char lds[49152];   // kg-merge
    __shared__ unsigned int nflag;
    __shared__ unsigned int flagbuf[128];
    __shared__ double fred[8];

    const int tid = threadIdx.x, lane = tid & 63, wv = tid >> 6;
    const int cg = wv & 3, kg = wv >> 2;
    const int rt = (int)blockIdx.x >> 2, b = (int)blockIdx.x & 3;
    if (tid == 0) nflag = 0;

    const unsigned char* bptr = Bp + (size_t)b * 786432 + kg * 12288 + cg * 1024 + lane * 16;
    const unsigned long long* mptr = tmask + (size_t)rt * 4096 + kg * 64 + lane;

    i32x4 acc[4][3];
#pragma unroll
    for (int r = 0; r < 4; ++r)
#pragma unroll
        for (int pl = 0; pl < 3; ++pl) {
            i32x4 z = {0, 0, 0, 0};
            acc[r][pl] = z;
        }

#define DECLSET(S) i32x4 b##S##0, b##S##1, b##S##2; unsigned long long m##S;
#define LOADSET(S, T) { const unsigned char* g_ = bptr + (size_t)(T) * 24576;          \
        b##S##0 = *(const i32x4*)(g_);                                                 \
        b##S##1 = *(const i32x4*)(g_ + 4096);                                          \
        b##S##2 = *(const i32x4*)(g_ + 8192);                                          \
        m##S = mptr[(size_t)(T) * 128]; }

    DECLSET(A) DECLSET(B) DECLSET(C) DECLSET(D)
    LOADSET(A, 0) LOADSET(B, 1) LOADSET(C, 2) LOADSET(D, 3)

    auto dostep = [&](unsigned long long mw, i32x4 v0, i32x4 v1, i32x4 v2) {
        const unsigned int mlo = (unsigned int)mw, mhi = (unsigned int)(mw >> 32);
#pragma unroll
        for (int r = 0; r < 4; ++r) {
            unsigned int half = (r >> 1) ? mhi : mlo;
            unsigned int w16 = (r & 1) ? (half >> 16) : (half & 0xFFFFu);
            uint32x4 u;
#pragma unroll
            for (int q = 0; q < 4; ++q)
                u[q] = (((w16 >> (4 * q)) & 0xFu) * 0x00204081u) & 0x01010101u;
            i32x4 af = __builtin_bit_cast(i32x4, u);
            acc[r][0] = __builtin_amdgcn_mfma_i32_16x16x64_i8(af, v0, acc[r][0], 0, 0, 0);
            acc[r][1] = __builtin_amdgcn_mfma_i32_16x16x64_i8(af, v1, acc[r][1], 0, 0, 0);
            acc[r][2] = __builtin_amdgcn_mfma_i32_16x16x64_i8(af, v2, acc[r][2], 0, 0, 0);
        }
    };

    for (int T = 0; T < 32; T += 4) {
        dostep(mA, bA0, bA1, bA2);
        if (T + 4 < 32) LOADSET(A, T + 4)
        dostep(mB, bB0, bB1, bB2);
        if (T + 5 < 32) LOADSET(B, T + 5)
        dostep(mC, bC0, bC1, bC2);
        if (T + 6 < 32) LOADSET(C, T + 6)
        dostep(mD, bD0, bD1, bD2);
        if (T + 7 < 32) LOADSET(D, T + 7)
    }
#undef DECLSET
#undef LOADSET

    // merge kg=1 partials into kg=0 via LDS
    __syncthreads();
    if (kg == 1) {
        unsigned char* dst = lds + cg * 12288 + lane * 192;
#pragma unroll
        for (int r = 0; r < 4; ++r)
#pragma unroll
            for (int pl = 0; pl < 3; ++pl)
                *(i32x4*)(dst + (r * 3 + pl) * 16) = acc[r][pl];
    }
    __syncthreads();
    if (kg == 0) {
        const unsigned char* s2 = lds + cg * 12288 + lane * 192;
#pragma unroll
        for (int r = 0; r < 4; ++r)
#pragma unroll
            for (int pl = 0; pl < 3; ++pl) {
                i32x4 v = *(const i32x4*)(s2 + (r * 3 + pl) * 16);
#pragma unroll
                for (int q = 0; q < 4; ++q) acc[r][pl][q] += v[q];
            }

        const int o = cg * 16 + (lane & 15);
#pragma unroll
        for (int r = 0; r < 4; ++r) {
#pragma unroll
            for (int q = 0; q < 4; ++q) {
                double S = (double)acc[r][0][q] + 256.0 * (double)acc[r][1][q]
                         + 65536.0 * (double)acc[r][2][q];     // exact integer
                int i = rt * 64 + r * 16 + (lane >> 4) * 4 + q;  // C/D row map (m89)
                size_t oi = ((size_t)b * GN + i) * FOUT + o;
                out[oi] = S < 0.0 ? 1.0f : 0.0f;
                if (fabs(S) <= 2048.0) {
                    unsigned int idx = atomicAdd(&nflag, 1u);
                    if (idx < 128) flagbuf[idx] = ((unsigned int)i << 6) | (unsigned int)o;
                }
            }
        }
    }

    // ---- in-block exact fixup (expected ~0.2 items/block) ----
    __syncthreads();
    unsigned int nf = nflag;
    if (nf > 128) nf = 128;
    for (unsigned int f = 0; f < nf; ++f) {
        unsigned int e = flagbuf[f];
        int o = e & 63;
        int i = (int)(e >> 6);
        int row16 = i & 15, r = (i >> 4) & 3;
        int s = tid >> 3, lg = (tid >> 1) & 3, hf = tid & 1;
        unsigned long long w = tmask[((size_t)rt * 64 + s) * 64 + (lg * 16 + row16)];
        double ps = 0.0;
        const double* hwc = hW + ((size_t)b * GN + s * 64 + lg * 16) * FOUT + o;
#pragma unroll
        for (int jj = hf * 8; jj < hf * 8 + 8; ++jj) {
            if ((w >> (r * 16 + jj)) & 1ull)
                ps += hwc[(size_t)jj * FOUT];
        }
#pragma unroll
        for (int d = 32; d >= 1; d >>= 1) ps += __shfl_down(ps, d, 64);
        if (lane == 0) fred[wv] = ps;
        __syncthreads();
        if (tid == 0) {
            double tot = ((fred[0] + fred[1]) + (fred[2] + fred[3]))
                       + ((fred[4] + fred[5]) + (fred[6] + fred[7]));
            out[((size_t)b * GN + i) * FOUT + o] = tot < 0.0 ? 1.0f : 0.0f;
        }
        __syncthreads();
    }
}

extern "C" void kernel_launch(void* const* d_in, const int* in_sizes, int n_in,
                              void* d_out, int out_size, void* d_ws, size_t ws_size,
                              hipStream_t stream) {
    const float* h   = (const float*)d_in[0];   // [4,4096,128]
    const int*   adj = (const int*)d_in[1];     // [4096,4096]
    const float* W   = (const float*)d_in[2];   // [128,64]
    float* out = (float*)d_out;                 // [4,4096,64] f32

    char* ws = (char*)d_ws;
    double* hW                = (double*)ws;                          // 8 MB @ 0
    unsigned char* Bp         = (unsigned char*)(ws + 8388608);       // 3 MB @ 8M
    unsigned long long* tmask = (unsigned long long*)(ws + 12582912); // 2 MB @ 12M

    pack_kernel<<<256, 1024, 0, stream>>>(adj, tmask);
    hwrepack_kernel<<<256, 512, 0, stream>>>(h, W, hW, Bp);
    gemm_kernel<<<256, 512, 0, stream>>>(Bp, tmask, hW, out);
}